// Round 2
// baseline (183.015 us; speedup 1.0000x reference)
//
#include <hip/hip_runtime.h>

#define BINS  30
#define NROWS 8192
#define NCOLS 2048
#define COLS_PER_BLK 256                 // grid.x = 8
#define ROWS_PER_BLK 128                 // grid.y = 64
#define YSLICES 64

#define FIXED_SCALE 16384.0f             // 2^14 fixed point for bce
#define CNT_SHIFT   24                   // count bit 24, sum in [0:24)
#define SUM_MASK    ((1u << CNT_SHIFT) - 1)
#define PK_MASK     ((1u << (CNT_SHIFT + 1)) - 1)   // sum + count bit

// ws layout (bytes):
//   part : u32[YSLICES][BINS][NCOLS]   (15.7 MB)
//   cnt  : float[BINS][NCOLS]          (245760 B)
//   bsum : float[BINS][NCOLS]          (245760 B)
//   blockPart: float[8]
//   ctr  : u32 (last-block-done counter)
#define WS_PART  0
#define WS_CNT   (YSLICES * BINS * NCOLS * 4)
#define WS_BSUM  (WS_CNT + BINS * NCOLS * 4)
#define WS_BPART (WS_BSUM + BINS * NCOLS * 4)
#define WS_CTR   (WS_BPART + 8 * 4)

// ---------------------------------------------------------------------------
// Kernel A (R2 rewrite): NO LDS ATOMICS.
// Theory: ds_add_u32 RMW throughput (~1 lane/cy/CU) was the 132k-cycle wall
// (65536 lane-atomics/CU == measured time; swizzle-neutral, VALU 25%,
// HBM 19% all consistent). Replace with exclusive-writer plain RMW:
//   phase1: 512 thr load 8 rows x 256 cols coalesced (wave w = row w,
//           lane covers 4 cols), pack (b<<27 | 1<<24 | bce_fix14) per elem,
//           ds_write_b128 to double-buffered staging tile Tb.
//   phase2: thread c (<256) EXCLUSIVELY owns column c: reads the 8 staged
//           rows, plain H[b*256+c] += (v & PK_MASK). No races by
//           construction; banks conflict-free (idx % 32 == c % 32).
// Double-buffered Tb -> ONE barrier per tile. 16 tiles of 8 rows.
// LDS 47104 B, 512 thr -> 2 blocks/CU, 16 waves/CU.
// Integer adds identical to old atomic packing -> part[] bit-identical.
// ---------------------------------------------------------------------------
__global__ __launch_bounds__(512, 4) void k_main(
    const float* __restrict__ preds, const int* __restrict__ targets,
    unsigned int* __restrict__ part, unsigned int* __restrict__ ctr)
{
    __shared__ __align__(16) unsigned int H[BINS * COLS_PER_BLK];   // 30720 B
    __shared__ __align__(16) unsigned int Tb[2][8 * COLS_PER_BLK];  // 16384 B
    const int t = threadIdx.x;
    if (blockIdx.x == 0 && blockIdx.y == 0 && t == 0) atomicExch(ctr, 0u);
    for (int i = t; i < BINS * COLS_PER_BLK; i += 512) H[i] = 0u;

    const int wrow = t >> 6;                 // 0..7: tile-row = wave id
    const int lane = t & 63;
    const int colBase = blockIdx.x * COLS_PER_BLK;
    const int col0 = colBase + 4 * lane;
    const int r0   = blockIdx.y * ROWS_PER_BLK + wrow;

    const float4* P = (const float4*)(preds   + (size_t)r0 * NCOLS + col0);
    const int4*   T = (const int4*)  (targets + (size_t)r0 * NCOLS + col0);
    const int RV8 = 8 * NCOLS / 4;           // 8 rows in float4 units

    // prologue: tile 0 in flight
    float4 pc = P[0];
    int4   tc = T[0];
    __syncthreads();                          // H zero visible

    #pragma unroll 2
    for (int tile = 0; tile < 16; ++tile) {
        // prefetch next tile (consumed after the barrier, next iteration)
        float4 pn; int4 tn;
        if (tile < 15) { P += RV8; T += RV8; pn = P[0]; tn = T[0]; }
        __builtin_amdgcn_sched_barrier(0);    // keep prefetch issued here

        // phase1: compute packed (bin | count | bce) and stage to Tb
        const float pv[4] = {pc.x, pc.y, pc.z, pc.w};
        const int   tv[4] = {tc.x, tc.y, tc.z, tc.w};
        unsigned int pk[4];
        #pragma unroll
        for (int j = 0; j < 4; ++j) {
            float p  = pv[j];
            float pp = tv[j] ? -p : p;                    // p'
            float e  = __expf(-fabsf(pp));                // exp(-|p'|)
            float d  = 1.0f + e;
            float r1 = __builtin_amdgcn_rcpf(d);
            float g  = (pp >= 0.0f) ? r1 : e * r1;        // sigmoid(p')
            int   b  = (int)(g * 30.0f);
            b = b > (BINS - 1) ? (BINS - 1) : b;
            float bce = fmaxf(pp, 0.0f) + __logf(d);      // softplus(p')
            pk[j] = ((unsigned int)b << 27) | (1u << CNT_SHIFT)
                  | (unsigned int)(bce * FIXED_SCALE + 0.5f);
        }
        uint4 w = make_uint4(pk[0], pk[1], pk[2], pk[3]);
        *((uint4*)&Tb[tile & 1][wrow * COLS_PER_BLK + 4 * lane]) = w;
        __syncthreads();

        // phase2: exclusive column owners, plain RMW (no atomics)
        if (t < COLS_PER_BLK) {
            unsigned int v[8];
            #pragma unroll
            for (int r = 0; r < 8; ++r)
                v[r] = Tb[tile & 1][r * COLS_PER_BLK + t];
            #pragma unroll
            for (int r = 0; r < 8; ++r) {
                const int idx = (int)(v[r] >> 27) * COLS_PER_BLK + t;
                H[idx] += v[r] & PK_MASK;     // compiler orders (may-alias)
            }
        }
        if (tile < 15) { pc = pn; tc = tn; }
    }
    __syncthreads();

    // flush: straight copy, coalesced
    const size_t outBase = (size_t)blockIdx.y * BINS * NCOLS + colBase;
    for (int i = t; i < BINS * COLS_PER_BLK; i += 512)
        part[outBase + (size_t)(i >> 8) * NCOLS + (i & 255)] = H[i];
}

// ---------------------------------------------------------------------------
// Kernel B: wide y-slice reduction with unpack (unchanged).
// ---------------------------------------------------------------------------
__global__ __launch_bounds__(256) void k_reduce(
    const unsigned int* __restrict__ part,
    float* __restrict__ cnt_f, float* __restrict__ bsum_f)
{
    const int id = blockIdx.x * 256 + threadIdx.x;    // 0 .. 61439
    unsigned int cnt = 0u, sm = 0u;
    #pragma unroll 16
    for (int y = 0; y < YSLICES; ++y) {
        const unsigned int v = part[(size_t)y * BINS * NCOLS + id];
        cnt += v >> CNT_SHIFT;
        sm  += v & SUM_MASK;
    }
    cnt_f[id]  = (float)cnt;
    bsum_f[id] = (float)sm * (1.0f / FIXED_SCALE);
}

// ---------------------------------------------------------------------------
// Kernel C: per-column contraction + fused final sum (last-block-done).
// All inter-block traffic through device-scope atomics (XCD-coherent);
// final 8-term sum in the same deterministic order as the old k_final.
// ---------------------------------------------------------------------------
__global__ __launch_bounds__(256) void k_colsum(
    const float* __restrict__ cnt_f, const float* __restrict__ bsum_f,
    const float* __restrict__ acc_sum, float* __restrict__ blockPart,
    unsigned int* __restrict__ ctr, float* __restrict__ out)
{
    __shared__ float wave_sums[4];
    const int tid = threadIdx.x;
    const int c   = blockIdx.x * 256 + tid;

    float colsum = 0.0f;
    int n = 0;
    #pragma unroll
    for (int b = 0; b < BINS; ++b) {
        const size_t gidx = (size_t)b * NCOLS + c;
        const float cnt = cnt_f[gidx];
        if (cnt >= 1.0f) {
            n += 1;
            float acc_new = 0.75f * acc_sum[gidx] + 0.25f * cnt;
            colsum += bsum_f[gidx] / acc_new;
        }
    }
    colsum /= (float)((n > 1 ? n : 1) * NCOLS);

    #pragma unroll
    for (int off = 32; off > 0; off >>= 1)
        colsum += __shfl_down(colsum, off, 64);
    if ((tid & 63) == 0) wave_sums[tid >> 6] = colsum;
    __syncthreads();
    if (tid == 0) {
        const float s = wave_sums[0] + wave_sums[1] + wave_sums[2] + wave_sums[3];
        atomicExch(&blockPart[blockIdx.x], s);    // coherent publish
        __threadfence();
        if (atomicAdd(ctr, 1u) == 7u) {           // last block finishes
            __threadfence();
            double d = 0.0;
            #pragma unroll
            for (int i = 0; i < 8; ++i)
                d += (double)atomicAdd(&blockPart[i], 0.0f);  // coherent fetch
            out[0] = (float)d;
        }
    }
}

extern "C" void kernel_launch(void* const* d_in, const int* in_sizes, int n_in,
                              void* d_out, int out_size, void* d_ws, size_t ws_size,
                              hipStream_t stream)
{
    const float* preds   = (const float*)d_in[0];
    const int*   targets = (const int*)d_in[1];
    const float* acc_sum = (const float*)d_in[2];

    unsigned int* part = (unsigned int*)((char*)d_ws + WS_PART);
    float* cnt_f       = (float*)((char*)d_ws + WS_CNT);
    float* bsum_f      = (float*)((char*)d_ws + WS_BSUM);
    float* blockPart   = (float*)((char*)d_ws + WS_BPART);
    unsigned int* ctr  = (unsigned int*)((char*)d_ws + WS_CTR);

    dim3 gA(NCOLS / COLS_PER_BLK, NROWS / ROWS_PER_BLK);   // (8, 64) = 512 blocks
    k_main<<<gA, 512, 0, stream>>>(preds, targets, part, ctr);

    k_reduce<<<(BINS * NCOLS) / 256, 256, 0, stream>>>(part, cnt_f, bsum_f);

    k_colsum<<<NCOLS / 256, 256, 0, stream>>>(cnt_f, bsum_f, acc_sum,
                                              blockPart, ctr, (float*)d_out);
}